// Round 7
// baseline (162.670 us; speedup 1.0000x reference)
//
#include <hip/hip_runtime.h>
#include <float.h>
#include <math.h>

#define B 128
#define D 128
#define N 3072      // 3*32*32
#define NP 4096     // next pow2 for bitonic sort
#define NZBLK 16    // z-role blocks (each does 8 rows of zcos)
#define TROW 64     // row-tiles (2 rows each)
#define NTILE (TROW*(TROW+1)/2)   // 2080 upper-tri 2x2 tiles
#define GRID 256    // 1 block/CU; grid <= capacity => all resident, no deadlock
#define MAGIC 0x5A5A5A5A          // != 0xAAAAAAAA poison, != 0
#define FSTRIDE 16                // flag padding (ints) to avoid false sharing

__device__ __forceinline__ void cas(float& a, float& b, bool up) {
    float lo = fminf(a, b), hi = fmaxf(a, b);
    a = up ? lo : hi;
    b = up ? hi : lo;
}

__device__ __forceinline__ void wait_flag(const int* f) {
    while (__hip_atomic_load(f, __ATOMIC_ACQUIRE, __HIP_MEMORY_SCOPE_AGENT) != MAGIC)
        __builtin_amdgcn_s_sleep(4);
}

__device__ __forceinline__ void set_flag(int* f) {
    __hip_atomic_store(f, MAGIC, __ATOMIC_RELEASE, __HIP_MEMORY_SCOPE_AGENT);
}

// ---------------------------------------------------------------------------
// Single fused kernel, flag-based producer-consumer sync (no grid.sync).
//  phase 1: bid 0..127  register/shfl bitonic sort of x row -> xs (R5 verbatim)
//           bid 128..143 zcos with inline L2-normalize      (R3 verbatim)
//           bid 144      zero the atomicAdd target
//           each role: __syncthreads (drains stores) then RELEASE-AGENT flag.
//  phase 2: all 256 blocks take 2x2 tiles T = bid + 256*w (w = wave 0..15),
//           ACQUIRE-AGENT poll of the needed flags only, then R6 tile math.
// ---------------------------------------------------------------------------
__global__ __launch_bounds__(1024) void fused_kernel(const float* __restrict__ x,
                                                     const float* __restrict__ z,
                                                     float* __restrict__ xs,
                                                     float* __restrict__ zcos,
                                                     int* __restrict__ flags,
                                                     float* __restrict__ out) {
    __shared__ float smem[NP];
    __shared__ float mx[2];
    __shared__ float partial[16];
    int tid = threadIdx.x;
    int bid = blockIdx.x;

    // ---------------- phase 1 ----------------
    if (bid < B) {
        // ----- sort role (validated R5/R6, verbatim) -----
        float* buf = smem;
        int row = bid;
        int base = tid * 4;
        float v[4];

        if (base < N) {
            float4 t4 = ((const float4*)(x + (size_t)row * N))[tid];
            v[0] = t4.x; v[1] = t4.y; v[2] = t4.z; v[3] = t4.w;
        } else {
            v[0] = v[1] = v[2] = v[3] = FLT_MAX;
        }

        for (int k = 2; k <= NP; k <<= 1) {
            int j = k >> 1;
            bool ub = ((base & k) == 0);

            if (j >= 256) {
                ((float4*)buf)[tid] = make_float4(v[0], v[1], v[2], v[3]);
                __syncthreads();
                for (; j >= 256; j >>= 1) {
                    #pragma unroll
                    for (int u = 0; u < 2; u++) {
                        int p = tid + u * 1024;
                        int i = ((p & ~(j - 1)) << 1) | (p & (j - 1));
                        int pj = i | j;
                        float a = buf[i], b2 = buf[pj];
                        bool up = ((i & k) == 0);
                        if ((a > b2) == up) { buf[i] = b2; buf[pj] = a; }
                    }
                    __syncthreads();
                }
                float4 t4 = ((float4*)buf)[tid];
                v[0] = t4.x; v[1] = t4.y; v[2] = t4.z; v[3] = t4.w;
                __syncthreads();
            }

            for (; j >= 4; j >>= 1) {
                int lx = j >> 2;
                bool keep_lower = ((tid & lx) == 0);
                bool sel = (keep_lower == ub);
                #pragma unroll
                for (int r = 0; r < 4; r++) {
                    float p = __shfl_xor(v[r], lx, 64);
                    v[r] = sel ? fminf(v[r], p) : fmaxf(v[r], p);
                }
            }
            if (j == 2) {
                cas(v[0], v[2], ub);
                cas(v[1], v[3], ub);
                j >>= 1;
            }
            {
                bool upA = (((base + 0) & k) == 0);
                bool upB = (((base + 2) & k) == 0);
                cas(v[0], v[1], upA);
                cas(v[2], v[3], upB);
            }
        }

        if (base < N)
            ((float4*)(xs + (size_t)row * N))[tid] = make_float4(v[0], v[1], v[2], v[3]);
        __syncthreads();               // drain all threads' stores (vmcnt(0))
        if (tid == 0) set_flag(&flags[bid * FSTRIDE]);
    } else if (bid < B + NZBLK) {
        // ----- z role (validated R3..R6, verbatim) -----
        float* inv_s = smem;
        {
            int row = tid >> 3;
            int seg = tid & 7;
            const float4* zr = (const float4*)(z + row * D + seg * 16);
            float s = 0.f;
            #pragma unroll
            for (int u = 0; u < 4; u++) {
                float4 v = zr[u];
                s += v.x * v.x + v.y * v.y + v.z * v.z + v.w * v.w;
            }
            s += __shfl_down(s, 4, 8);
            s += __shfl_down(s, 2, 8);
            s += __shfl_down(s, 1, 8);
            if (seg == 0) inv_s[row] = 1.0f / fmaxf(sqrtf(s), 1e-12f);
        }
        __syncthreads();

        int gi = (bid - B) * 8 + (tid >> 7);
        int j  = tid & 127;
        const float4* zi = (const float4*)(z + gi * D);
        const float4* zj = (const float4*)(z + j * D);
        float dot = 0.f;
        #pragma unroll 8
        for (int k4 = 0; k4 < D / 4; k4++) {
            float4 a = zi[k4], b = zj[k4];
            dot += a.x * b.x + a.y * b.y + a.z * b.z + a.w * b.w;
        }
        zcos[gi * B + j] = dot * inv_s[gi] * inv_s[j];
        __syncthreads();               // drain stores
        if (tid == 0) set_flag(&flags[bid * FSTRIDE]);   // flags 128..143
    } else if (bid == B + NZBLK) {
        if (tid == 0) {
            out[0] = 0.f;
            set_flag(&flags[(B + NZBLK) * FSTRIDE]);     // flag 144 (same-thread release)
        }
    }
    // blocks 145..255: straight to phase 2

    // ---------------- phase 2 ----------------
    // wait for all zcos flags + out-zero flag (block-wide, one flag/thread)
    if (tid < NZBLK + 1) {
        wait_flag(&flags[(B + tid) * FSTRIDE]);
    }
    __syncthreads();

    // per-block diagonal max of zcos (max attained on diagonal)
    if (tid < B) {
        float v = zcos[tid * (B + 1)];
        #pragma unroll
        for (int o = 32; o > 0; o >>= 1) v = fmaxf(v, __shfl_down(v, o, 64));
        if ((tid & 63) == 0) mx[tid >> 6] = v;
    }
    __syncthreads();
    float maxv = fmaxf(mx[0], mx[1]);

    int w = tid >> 6;                  // wave 0..15
    int lane = tid & 63;
    float wacc = 0.f;                  // lane0-valid accumulator

    for (int T = bid + GRID * w; T < NTILE; T += GRID * 16) {
        // decode T -> (ti, tj), ti<=tj over TROW=64 (validated R6)
        float ff = (float)(2 * TROW + 1);
        int ti = (int)((ff - sqrtf(ff * ff - 8.0f * (float)T)) * 0.5f);
        if (ti < 0) ti = 0;
        if (ti > TROW - 1) ti = TROW - 1;
        while ((ti + 1) * TROW - ((ti + 1) * ti) / 2 <= T) ti++;
        while (ti * TROW - (ti * (ti - 1)) / 2 > T) ti--;
        int tj = ti + (T - (ti * TROW - (ti * (ti - 1)) / 2));

        int r0 = 2 * ti, r1 = r0 + 1;
        int c0 = 2 * tj, c1 = c0 + 1;

        // wait for the 4 source rows (all lanes poll same addr -> broadcast)
        wait_flag(&flags[r0 * FSTRIDE]);
        wait_flag(&flags[r1 * FSTRIDE]);
        wait_flag(&flags[c0 * FSTRIDE]);
        wait_flag(&flags[c1 * FSTRIDE]);

        const float4* a0 = (const float4*)(xs + (size_t)r0 * N);
        const float4* a1 = (const float4*)(xs + (size_t)r1 * N);
        const float4* b0 = (const float4*)(xs + (size_t)c0 * N);
        const float4* b1 = (const float4*)(xs + (size_t)c1 * N);

        float s00 = 0.f, s01 = 0.f, s10 = 0.f, s11 = 0.f;
        #pragma unroll
        for (int u = 0; u < N / 4 / 64; u++) {      // 12 iterations
            int idx = lane + u * 64;
            float4 va0 = a0[idx], va1 = a1[idx];
            float4 vb0 = b0[idx], vb1 = b1[idx];
            s00 += fabsf(va0.x - vb0.x) + fabsf(va0.y - vb0.y)
                 + fabsf(va0.z - vb0.z) + fabsf(va0.w - vb0.w);
            s01 += fabsf(va0.x - vb1.x) + fabsf(va0.y - vb1.y)
                 + fabsf(va0.z - vb1.z) + fabsf(va0.w - vb1.w);
            s10 += fabsf(va1.x - vb0.x) + fabsf(va1.y - vb0.y)
                 + fabsf(va1.z - vb0.z) + fabsf(va1.w - vb0.w);
            s11 += fabsf(va1.x - vb1.x) + fabsf(va1.y - vb1.y)
                 + fabsf(va1.z - vb1.z) + fabsf(va1.w - vb1.w);
        }
        #pragma unroll
        for (int o = 32; o > 0; o >>= 1) {
            s00 += __shfl_down(s00, o, 64);
            s01 += __shfl_down(s01, o, 64);
            s10 += __shfl_down(s10, o, 64);
            s11 += __shfl_down(s11, o, 64);
        }
        if (lane == 0) {
            bool diag = (ti == tj);
            float w00 = diag ? 1.0f : 2.0f;
            float w01 = 2.0f;
            float w10 = diag ? 0.0f : 2.0f;
            float w11 = diag ? 1.0f : 2.0f;
            float inv_n = 1.0f / N;
            float d00 = s00 * inv_n - (maxv - zcos[r0 * B + c0]);
            float d01 = s01 * inv_n - (maxv - zcos[r0 * B + c1]);
            float d10 = s10 * inv_n - (maxv - zcos[r1 * B + c0]);
            float d11 = s11 * inv_n - (maxv - zcos[r1 * B + c1]);
            wacc += w00 * d00 * d00 + w01 * d01 * d01
                  + w10 * d10 * d10 + w11 * d11 * d11;
        }
    }

    if (lane == 0) partial[w] = wacc;  // all 16 waves write (0 if no tile)
    __syncthreads();
    if (tid == 0) {
        float blk = 0.f;
        #pragma unroll
        for (int u = 0; u < 16; u++) blk += partial[u];
        atomicAdd(out, blk * (1.0f / (B * B)));
    }
}

extern "C" void kernel_launch(void* const* d_in, const int* in_sizes, int n_in,
                              void* d_out, int out_size, void* d_ws, size_t ws_size,
                              hipStream_t stream) {
    const float* z = (const float*)d_in[0];   // [128,128]
    const float* x = (const float*)d_in[1];   // [128,3,32,32]
    float* out = (float*)d_out;               // [1]
    float* ws = (float*)d_ws;

    float* zcos = ws;                         // 16384 floats
    float* xs   = ws + 16384;                 // 393216 floats (16B-aligned)
    int*   flags = (int*)(ws + 16384 + 393216);  // 145*FSTRIDE ints

    fused_kernel<<<GRID, 1024, 0, stream>>>(x, z, xs, zcos, flags, out);
}

// Round 8
// 89.882 us; speedup vs baseline: 1.8098x; 1.8098x over previous
//
#include <hip/hip_runtime.h>
#include <float.h>
#include <math.h>

#define B 128
#define D 128
#define N 3072      // 3*32*32
#define NP 4096     // next pow2 for bitonic sort
#define NZBLK 16    // z-role blocks (each does 8 rows of zcos)
#define TROW 32     // row-tiles (4 rows each)
#define NTILE (TROW*(TROW+1)/2)   // 528 upper-tri 4x4 tiles
#define PAIR_BLOCKS (NTILE/4)     // 132 blocks x 4 waves, exact

__device__ __forceinline__ void cas(float& a, float& b, bool up) {
    float lo = fminf(a, b), hi = fmaxf(a, b);
    a = up ? lo : hi;
    b = up ? hi : lo;
}

// ---------------------------------------------------------------------------
// K1 prep (validated R5/R6): blocks 0..127 register/shfl bitonic sort of x
// rows; blocks 128..143 zcos with inline L2-normalize; block 144 zeroes out.
// ---------------------------------------------------------------------------
__global__ __launch_bounds__(1024) void prep_kernel(const float* __restrict__ x,
                                                    const float* __restrict__ z,
                                                    float* __restrict__ xs,
                                                    float* __restrict__ zcos,
                                                    float* __restrict__ out) {
    __shared__ float smem[NP];
    int tid = threadIdx.x;
    int bid = blockIdx.x;

    if (bid < B) {
        float* buf = smem;
        int row = bid;
        int base = tid * 4;
        float v[4];

        if (base < N) {
            float4 t4 = ((const float4*)(x + (size_t)row * N))[tid];
            v[0] = t4.x; v[1] = t4.y; v[2] = t4.z; v[3] = t4.w;
        } else {
            v[0] = v[1] = v[2] = v[3] = FLT_MAX;
        }

        for (int k = 2; k <= NP; k <<= 1) {
            int j = k >> 1;
            bool ub = ((base & k) == 0);

            if (j >= 256) {
                ((float4*)buf)[tid] = make_float4(v[0], v[1], v[2], v[3]);
                __syncthreads();
                for (; j >= 256; j >>= 1) {
                    #pragma unroll
                    for (int u = 0; u < 2; u++) {
                        int p = tid + u * 1024;
                        int i = ((p & ~(j - 1)) << 1) | (p & (j - 1));
                        int pj = i | j;
                        float a = buf[i], b2 = buf[pj];
                        bool up = ((i & k) == 0);
                        if ((a > b2) == up) { buf[i] = b2; buf[pj] = a; }
                    }
                    __syncthreads();
                }
                float4 t4 = ((float4*)buf)[tid];
                v[0] = t4.x; v[1] = t4.y; v[2] = t4.z; v[3] = t4.w;
                __syncthreads();
            }

            for (; j >= 4; j >>= 1) {
                int lx = j >> 2;
                bool keep_lower = ((tid & lx) == 0);
                bool sel = (keep_lower == ub);
                #pragma unroll
                for (int r = 0; r < 4; r++) {
                    float p = __shfl_xor(v[r], lx, 64);
                    v[r] = sel ? fminf(v[r], p) : fmaxf(v[r], p);
                }
            }
            if (j == 2) {
                cas(v[0], v[2], ub);
                cas(v[1], v[3], ub);
                j >>= 1;
            }
            {
                bool upA = (((base + 0) & k) == 0);
                bool upB = (((base + 2) & k) == 0);
                cas(v[0], v[1], upA);
                cas(v[2], v[3], upB);
            }
        }

        if (base < N)
            ((float4*)(xs + (size_t)row * N))[tid] = make_float4(v[0], v[1], v[2], v[3]);
    } else if (bid < B + NZBLK) {
        float* inv_s = smem;           // [128] inverse norms
        {
            int row = tid >> 3;
            int seg = tid & 7;
            const float4* zr = (const float4*)(z + row * D + seg * 16);
            float s = 0.f;
            #pragma unroll
            for (int u = 0; u < 4; u++) {
                float4 v = zr[u];
                s += v.x * v.x + v.y * v.y + v.z * v.z + v.w * v.w;
            }
            s += __shfl_down(s, 4, 8);
            s += __shfl_down(s, 2, 8);
            s += __shfl_down(s, 1, 8);
            if (seg == 0) inv_s[row] = 1.0f / fmaxf(sqrtf(s), 1e-12f);
        }
        __syncthreads();

        int gi = (bid - B) * 8 + (tid >> 7);
        int j  = tid & 127;
        const float4* zi = (const float4*)(z + gi * D);
        const float4* zj = (const float4*)(z + j * D);
        float dot = 0.f;
        #pragma unroll 8
        for (int k4 = 0; k4 < D / 4; k4++) {
            float4 a = zi[k4], b = zj[k4];
            dot += a.x * b.x + a.y * b.y + a.z * b.z + a.w * b.w;
        }
        zcos[gi * B + j] = dot * inv_s[gi] * inv_s[j];
    } else if (tid == 0) {
        out[0] = 0.f;
    }
}

// ---------------------------------------------------------------------------
// K2 pair: one 4x4 row-tile per wave — 16 pairs from 8 row-reads (0.5 reads
// per pair; halves L2 traffic vs R6's 2x2). 132 blocks x 256 threads = 528
// tiles exact. Diagonal tiles weight (p<q)?2:(p==q)?1:0; off-diag weight 2;
// union reconstructs the full symmetric B^2 sum (496*32 + 32*16 = 16384).
// ---------------------------------------------------------------------------
__global__ __launch_bounds__(256) void pair_kernel(const float* __restrict__ xs,
                                                   const float* __restrict__ zcos,
                                                   float* __restrict__ out) {
    __shared__ float mx[2];
    __shared__ float partial[4];
    int tid = threadIdx.x;

    // diagonal max of zcos (max attained on diagonal), 2 waves
    if (tid < B) {
        float v = zcos[tid * (B + 1)];
        #pragma unroll
        for (int o = 32; o > 0; o >>= 1) v = fmaxf(v, __shfl_down(v, o, 64));
        if ((tid & 63) == 0) mx[tid >> 6] = v;
    }
    __syncthreads();
    float maxv = fmaxf(mx[0], mx[1]);

    int w = tid >> 6;                  // wave 0..3
    int lane = tid & 63;
    int T = blockIdx.x * 4 + w;        // tile index, always < NTILE (528)

    // decode T -> (ti, tj), ti<=tj over TROW=32 (validated decode pattern)
    float ff = (float)(2 * TROW + 1);
    int ti = (int)((ff - sqrtf(ff * ff - 8.0f * (float)T)) * 0.5f);
    if (ti < 0) ti = 0;
    if (ti > TROW - 1) ti = TROW - 1;
    while ((ti + 1) * TROW - ((ti + 1) * ti) / 2 <= T) ti++;
    while (ti * TROW - (ti * (ti - 1)) / 2 > T) ti--;
    int tj = ti + (T - (ti * TROW - (ti * (ti - 1)) / 2));

    int r = 4 * ti;
    int c = 4 * tj;

    const float4* ap[4];
    const float4* bp[4];
    #pragma unroll
    for (int p = 0; p < 4; p++) {
        ap[p] = (const float4*)(xs + (size_t)(r + p) * N);
        bp[p] = (const float4*)(xs + (size_t)(c + p) * N);
    }

    float s[16];
    #pragma unroll
    for (int p = 0; p < 16; p++) s[p] = 0.f;

    #pragma unroll 4
    for (int u = 0; u < N / 4 / 64; u++) {          // 12 iterations
        int idx = lane + u * 64;
        float4 va[4], vb[4];
        #pragma unroll
        for (int p = 0; p < 4; p++) { va[p] = ap[p][idx]; vb[p] = bp[p][idx]; }
        #pragma unroll
        for (int p = 0; p < 4; p++) {
            #pragma unroll
            for (int q = 0; q < 4; q++) {
                s[p * 4 + q] += fabsf(va[p].x - vb[q].x) + fabsf(va[p].y - vb[q].y)
                              + fabsf(va[p].z - vb[q].z) + fabsf(va[p].w - vb[q].w);
            }
        }
    }
    #pragma unroll
    for (int p = 0; p < 16; p++) {
        #pragma unroll
        for (int o = 32; o > 0; o >>= 1) s[p] += __shfl_down(s[p], o, 64);
    }

    if (lane == 0) {
        bool diag = (ti == tj);
        float inv_n = 1.0f / N;
        float acc = 0.f;
        #pragma unroll
        for (int p = 0; p < 4; p++) {
            #pragma unroll
            for (int q = 0; q < 4; q++) {
                float wgt = diag ? ((p < q) ? 2.0f : ((p == q) ? 1.0f : 0.0f)) : 2.0f;
                float d = s[p * 4 + q] * inv_n - (maxv - zcos[(r + p) * B + (c + q)]);
                acc += wgt * d * d;
            }
        }
        partial[w] = acc;
    }
    __syncthreads();
    if (tid == 0) {
        float blk = partial[0] + partial[1] + partial[2] + partial[3];
        atomicAdd(out, blk * (1.0f / (B * B)));
    }
}

extern "C" void kernel_launch(void* const* d_in, const int* in_sizes, int n_in,
                              void* d_out, int out_size, void* d_ws, size_t ws_size,
                              hipStream_t stream) {
    const float* z = (const float*)d_in[0];   // [128,128]
    const float* x = (const float*)d_in[1];   // [128,3,32,32]
    float* out = (float*)d_out;               // [1]
    float* ws = (float*)d_ws;

    float* zcos = ws;                         // 16384 floats
    float* xs   = ws + 16384;                 // 393216 floats

    prep_kernel<<<B + NZBLK + 1, 1024, 0, stream>>>(x, z, xs, zcos, out);
    pair_kernel<<<PAIR_BLOCKS, 256, 0, stream>>>(xs, zcos, out);
}

// Round 9
// 86.690 us; speedup vs baseline: 1.8765x; 1.0368x over previous
//
#include <hip/hip_runtime.h>
#include <float.h>
#include <math.h>

#define B 128
#define D 128
#define N 3072      // 3*32*32
#define NP 4096     // next pow2 for bitonic sort
#define NZBLK 16    // z-role blocks (each does 8 rows of zcos)
#define TROW 64     // row-tiles (2 rows each)
#define NTILE (TROW*(TROW+1)/2)   // 2080 upper-tri 2x2 tiles
#define PAIR_BLOCKS (NTILE/4)     // 520 blocks x 4 waves, exact

__device__ __forceinline__ void cas(float& a, float& b, bool up) {
    float lo = fminf(a, b), hi = fmaxf(a, b);
    a = up ? lo : hi;
    b = up ? hi : lo;
}

// ---------------------------------------------------------------------------
// K1 prep (validated R5/R6): blocks 0..127 register/shfl bitonic sort of x
// rows; blocks 128..143 zcos with inline L2-normalize; block 144 zeroes out.
// ---------------------------------------------------------------------------
__global__ __launch_bounds__(1024) void prep_kernel(const float* __restrict__ x,
                                                    const float* __restrict__ z,
                                                    float* __restrict__ xs,
                                                    float* __restrict__ zcos,
                                                    float* __restrict__ out) {
    __shared__ float smem[NP];
    int tid = threadIdx.x;
    int bid = blockIdx.x;

    if (bid < B) {
        float* buf = smem;
        int row = bid;
        int base = tid * 4;
        float v[4];

        if (base < N) {
            float4 t4 = ((const float4*)(x + (size_t)row * N))[tid];
            v[0] = t4.x; v[1] = t4.y; v[2] = t4.z; v[3] = t4.w;
        } else {
            v[0] = v[1] = v[2] = v[3] = FLT_MAX;
        }

        for (int k = 2; k <= NP; k <<= 1) {
            int j = k >> 1;
            bool ub = ((base & k) == 0);

            if (j >= 256) {
                ((float4*)buf)[tid] = make_float4(v[0], v[1], v[2], v[3]);
                __syncthreads();
                for (; j >= 256; j >>= 1) {
                    #pragma unroll
                    for (int u = 0; u < 2; u++) {
                        int p = tid + u * 1024;
                        int i = ((p & ~(j - 1)) << 1) | (p & (j - 1));
                        int pj = i | j;
                        float a = buf[i], b2 = buf[pj];
                        bool up = ((i & k) == 0);
                        if ((a > b2) == up) { buf[i] = b2; buf[pj] = a; }
                    }
                    __syncthreads();
                }
                float4 t4 = ((float4*)buf)[tid];
                v[0] = t4.x; v[1] = t4.y; v[2] = t4.z; v[3] = t4.w;
                __syncthreads();
            }

            for (; j >= 4; j >>= 1) {
                int lx = j >> 2;
                bool keep_lower = ((tid & lx) == 0);
                bool sel = (keep_lower == ub);
                #pragma unroll
                for (int r = 0; r < 4; r++) {
                    float p = __shfl_xor(v[r], lx, 64);
                    v[r] = sel ? fminf(v[r], p) : fmaxf(v[r], p);
                }
            }
            if (j == 2) {
                cas(v[0], v[2], ub);
                cas(v[1], v[3], ub);
                j >>= 1;
            }
            {
                bool upA = (((base + 0) & k) == 0);
                bool upB = (((base + 2) & k) == 0);
                cas(v[0], v[1], upA);
                cas(v[2], v[3], upB);
            }
        }

        if (base < N)
            ((float4*)(xs + (size_t)row * N))[tid] = make_float4(v[0], v[1], v[2], v[3]);
    } else if (bid < B + NZBLK) {
        float* inv_s = smem;           // [128] inverse norms
        {
            int row = tid >> 3;
            int seg = tid & 7;
            const float4* zr = (const float4*)(z + row * D + seg * 16);
            float s = 0.f;
            #pragma unroll
            for (int u = 0; u < 4; u++) {
                float4 v = zr[u];
                s += v.x * v.x + v.y * v.y + v.z * v.z + v.w * v.w;
            }
            s += __shfl_down(s, 4, 8);
            s += __shfl_down(s, 2, 8);
            s += __shfl_down(s, 1, 8);
            if (seg == 0) inv_s[row] = 1.0f / fmaxf(sqrtf(s), 1e-12f);
        }
        __syncthreads();

        int gi = (bid - B) * 8 + (tid >> 7);
        int j  = tid & 127;
        const float4* zi = (const float4*)(z + gi * D);
        const float4* zj = (const float4*)(z + j * D);
        float dot = 0.f;
        #pragma unroll 8
        for (int k4 = 0; k4 < D / 4; k4++) {
            float4 a = zi[k4], b = zj[k4];
            dot += a.x * b.x + a.y * b.y + a.z * b.z + a.w * b.w;
        }
        zcos[gi * B + j] = dot * inv_s[gi] * inv_s[j];
    } else if (tid == 0) {
        out[0] = 0.f;
    }
}

// ---------------------------------------------------------------------------
// K2 pair (validated R6, best measured): one 2x2 row-tile per wave (4 pairs
// from 4 row-reads). 520 blocks x 256 threads (4 waves) = 2080 tiles exact.
// Diagonal tiles use weights {1,2,0,1}; off-diag weight 2 each — union over
// tiles reconstructs the full symmetric B^2 sum.
// ---------------------------------------------------------------------------
__global__ __launch_bounds__(256) void pair_kernel(const float* __restrict__ xs,
                                                   const float* __restrict__ zcos,
                                                   float* __restrict__ out) {
    __shared__ float mx[2];
    __shared__ float partial[4];
    int tid = threadIdx.x;

    // diagonal max of zcos (max attained on diagonal), 2 waves
    if (tid < B) {
        float v = zcos[tid * (B + 1)];
        #pragma unroll
        for (int o = 32; o > 0; o >>= 1) v = fmaxf(v, __shfl_down(v, o, 64));
        if ((tid & 63) == 0) mx[tid >> 6] = v;
    }
    __syncthreads();
    float maxv = fmaxf(mx[0], mx[1]);

    int w = tid >> 6;                  // wave 0..3
    int lane = tid & 63;
    int T = blockIdx.x * 4 + w;        // tile index, always < NTILE

    // decode T -> (ti, tj), ti<=tj over TROW=64 (validated decode pattern)
    float ff = (float)(2 * TROW + 1);
    int ti = (int)((ff - sqrtf(ff * ff - 8.0f * (float)T)) * 0.5f);
    if (ti < 0) ti = 0;
    if (ti > TROW - 1) ti = TROW - 1;
    while ((ti + 1) * TROW - ((ti + 1) * ti) / 2 <= T) ti++;
    while (ti * TROW - (ti * (ti - 1)) / 2 > T) ti--;
    int tj = ti + (T - (ti * TROW - (ti * (ti - 1)) / 2));

    int r0 = 2 * ti, r1 = r0 + 1;
    int c0 = 2 * tj, c1 = c0 + 1;

    const float4* a0 = (const float4*)(xs + (size_t)r0 * N);
    const float4* a1 = (const float4*)(xs + (size_t)r1 * N);
    const float4* b0 = (const float4*)(xs + (size_t)c0 * N);
    const float4* b1 = (const float4*)(xs + (size_t)c1 * N);

    float s00 = 0.f, s01 = 0.f, s10 = 0.f, s11 = 0.f;
    #pragma unroll
    for (int u = 0; u < N / 4 / 64; u++) {          // 12 iterations
        int idx = lane + u * 64;
        float4 va0 = a0[idx], va1 = a1[idx];
        float4 vb0 = b0[idx], vb1 = b1[idx];
        s00 += fabsf(va0.x - vb0.x) + fabsf(va0.y - vb0.y)
             + fabsf(va0.z - vb0.z) + fabsf(va0.w - vb0.w);
        s01 += fabsf(va0.x - vb1.x) + fabsf(va0.y - vb1.y)
             + fabsf(va0.z - vb1.z) + fabsf(va0.w - vb1.w);
        s10 += fabsf(va1.x - vb0.x) + fabsf(va1.y - vb0.y)
             + fabsf(va1.z - vb0.z) + fabsf(va1.w - vb0.w);
        s11 += fabsf(va1.x - vb1.x) + fabsf(va1.y - vb1.y)
             + fabsf(va1.z - vb1.z) + fabsf(va1.w - vb1.w);
    }
    #pragma unroll
    for (int o = 32; o > 0; o >>= 1) {
        s00 += __shfl_down(s00, o, 64);
        s01 += __shfl_down(s01, o, 64);
        s10 += __shfl_down(s10, o, 64);
        s11 += __shfl_down(s11, o, 64);
    }
    if (lane == 0) {
        bool diag = (ti == tj);
        float w00 = diag ? 1.0f : 2.0f;
        float w01 = 2.0f;
        float w10 = diag ? 0.0f : 2.0f;
        float w11 = diag ? 1.0f : 2.0f;
        float inv_n = 1.0f / N;
        float d00 = s00 * inv_n - (maxv - zcos[r0 * B + c0]);
        float d01 = s01 * inv_n - (maxv - zcos[r0 * B + c1]);
        float d10 = s10 * inv_n - (maxv - zcos[r1 * B + c0]);
        float d11 = s11 * inv_n - (maxv - zcos[r1 * B + c1]);
        partial[w] = w00 * d00 * d00 + w01 * d01 * d01
                   + w10 * d10 * d10 + w11 * d11 * d11;
    }
    __syncthreads();
    if (tid == 0) {
        float blk = partial[0] + partial[1] + partial[2] + partial[3];
        atomicAdd(out, blk * (1.0f / (B * B)));
    }
}

extern "C" void kernel_launch(void* const* d_in, const int* in_sizes, int n_in,
                              void* d_out, int out_size, void* d_ws, size_t ws_size,
                              hipStream_t stream) {
    const float* z = (const float*)d_in[0];   // [128,128]
    const float* x = (const float*)d_in[1];   // [128,3,32,32]
    float* out = (float*)d_out;               // [1]
    float* ws = (float*)d_ws;

    float* zcos = ws;                         // 16384 floats
    float* xs   = ws + 16384;                 // 393216 floats

    prep_kernel<<<B + NZBLK + 1, 1024, 0, stream>>>(x, z, xs, zcos, out);
    pair_kernel<<<PAIR_BLOCKS, 256, 0, stream>>>(xs, zcos, out);
}